// Round 11
// baseline (527.949 us; speedup 1.0000x reference)
//
#include <hip/hip_runtime.h>

// FlipFlopLoss forward DP, round 9 = R8 superstep structure + the missing
// lgkmcnt discipline for inline-asm ds_read (R8's NaN root cause).
//
// new[p] = logaddexp(prev[p-1] + x[move_idx[p-1]], prev[p] + x[stay_idx[p]])
//
// 1 block/batch, 4 waves x 4 positions/lane. Wave w covers 256 positions from
// startw = 125w-40 (wave0: 0), owns [125w, 125w+125). Ghost depth 40 => ONE
// barrier per 40 steps (superstep = 10 windows x 4 steps). Wave w publishes
// exact positions [125(w+1)-40, 125(w+1)) pre-barrier; wave w+1 lanes 0..9
// refresh their ghost post-barrier.
// x staged into 2 half-buffers of 10 windows (f32x4 time-minor, transposed
// for free by global_load_lds per-lane source addressing). Wave0 issues next
// superstep's 30 loads at superstep TOP; vmcnt(0) at the boundary is free.
//
// R9 fix: the compiler inserts NO waitcnt for asm-volatile ds_read outputs.
// Every GATHER prefetch is now followed by s_waitcnt lgkmcnt(8) (drains the
// PREVIOUS window's 8 reads; LDS returns in-order) + sched_barrier(0) so
// hipcc can't hoist the dependent VALU above the wait (guide rule #18).
// Last window: lgkmcnt(0) before COMPUTE. R6/R7 were only correct because
// their per-window lgkmcnt(0)+barrier sat between GATHER and use.

typedef float f32x4 __attribute__((ext_vector_type(4)));

constexpr int NT   = 4000;
constexpr int NB   = 128;
constexpr int NF   = 40;
constexpr int NPOS = 500;
constexpr int WPS  = 10;            // windows per superstep
constexpr int NSS  = NT / (WPS*4);  // 100 supersteps
constexpr int OWN  = 125;
constexpr int GH   = 40;
constexpr float C_SCALE   = 1.4426950408889634f;           // SHARP * log2(e)
constexpr float OUT_SCALE = -0.6931471805599453f / 4000.f; // -ln2 / (SHARP*NT)
constexpr float NEGF = -1e30f;

__device__ __forceinline__ float dpp_shr1(float v) {
    // lane i gets lane i-1's v; lane 0 keeps old = NEGF (bound_ctrl=0).
    int r = __builtin_amdgcn_update_dpp(
        __float_as_int(NEGF), __float_as_int(v),
        0x138 /*wave_shr:1*/, 0xF, 0xF, false);
    return __int_as_float(r);
}

__device__ __forceinline__ float lae2(float A, float B) {
    float mx = fmaxf(A, B);
    float d  = A - B;
    return mx + __log2f(1.0f + exp2f(-fabsf(d)));   // neg/abs fold into v_exp
}

__global__ void __launch_bounds__(256, 1) flipflop_fwd(
    const float* __restrict__ x,         // [NT, NB, NF]
    const int*   __restrict__ move_idx,  // [NB, NPOS-1]
    const int*   __restrict__ stay_idx,  // [NB, NPOS]
    const int*   __restrict__ seqlens,   // [NB]
    float*       __restrict__ out)       // [NB]
{
    const int b    = blockIdx.x;
    const int tid  = threadIdx.x;
    const int lane = tid & 63;
    const int wv   = tid >> 6;

    __shared__ f32x4 xbuf[2][WPS][NF];  // [half][win][f] -> 4 t-values; 12.8KB
    __shared__ float exh[2][3][GH];     // [superstep parity][boundary][40]

    // ---- position mapping ----
    const int startw = (wv == 0) ? 0 : (OWN * wv - GH);
    const int pb = startw + 4 * lane;   // this lane's first position

    // per-position gather indices (positions > 499 clamped; values unused)
    const int q0 = pb + 0 > 499 ? 499 : pb + 0;
    const int q1 = pb + 1 > 499 ? 499 : pb + 1;
    const int q2 = pb + 2 > 499 ? 499 : pb + 2;
    const int q3 = pb + 3 > 499 ? 499 : pb + 3;
    const int s0 = stay_idx[b * NPOS + q0];
    const int s1 = stay_idx[b * NPOS + q1];
    const int s2 = stay_idx[b * NPOS + q2];
    const int s3 = stay_idx[b * NPOS + q3];
    const int m0 = move_idx[b * (NPOS - 1) + (q0 >= 1 ? q0 - 1 : 0)];
    const int m1 = move_idx[b * (NPOS - 1) + (q1 >= 1 ? q1 - 1 : 0)];
    const int m2 = move_idx[b * (NPOS - 1) + (q2 >= 1 ? q2 - 1 : 0)];
    const int m3 = move_idx[b * (NPOS - 1) + (q3 >= 1 ? q3 - 1 : 0)];

    float F0 = (pb == 0) ? 0.0f : NEGF;
    float F1 = NEGF, F2 = NEGF, F3 = NEGF;

    // ---- LDS gather addresses: buf base + idx*16; (half,win) via offset: ----
    unsigned base_u = (unsigned)(unsigned long long)
        (__attribute__((address_space(3))) char*)&xbuf[0][0][0];
    const unsigned aS0 = base_u + (unsigned)s0 * 16u;
    const unsigned aM0 = base_u + (unsigned)m0 * 16u;
    const unsigned aS1 = base_u + (unsigned)s1 * 16u;
    const unsigned aM1 = base_u + (unsigned)m1 * 16u;
    const unsigned aS2 = base_u + (unsigned)s2 * 16u;
    const unsigned aM2 = base_u + (unsigned)m2 * 16u;
    const unsigned aS3 = base_u + (unsigned)s3 * 16u;
    const unsigned aM3 = base_u + (unsigned)m3 * 16u;

    f32x4 g[2][8];   // [win parity][s0,m0,s1,m1,s2,m2,s3,m3]; static idx only

#define DSR(DST, ADDR, OFS)                                                     \
    asm volatile("ds_read_b128 %0, %1 offset:%c2"                               \
                 : "=v"(DST) : "v"(ADDR), "i"(OFS))

#define GATHER(H, WIN, G) do {                                                  \
    DSR(g[G][0], aS0, ((H) * WPS + (WIN)) * 640);                               \
    DSR(g[G][1], aM0, ((H) * WPS + (WIN)) * 640);                               \
    DSR(g[G][2], aS1, ((H) * WPS + (WIN)) * 640);                               \
    DSR(g[G][3], aM1, ((H) * WPS + (WIN)) * 640);                               \
    DSR(g[G][4], aS2, ((H) * WPS + (WIN)) * 640);                               \
    DSR(g[G][5], aM2, ((H) * WPS + (WIN)) * 640);                               \
    DSR(g[G][6], aS3, ((H) * WPS + (WIN)) * 640);                               \
    DSR(g[G][7], aM3, ((H) * WPS + (WIN)) * 640);                               \
} while (0)

#define COMPUTE(G) do {                                                         \
    _Pragma("unroll")                                                           \
    for (int i = 0; i < 4; ++i) {                                               \
        float nb = dpp_shr1(F3);                                                \
        float xa0 = fmaf(g[G][1][i], C_SCALE, nb);                              \
        float xb0 = fmaf(g[G][0][i], C_SCALE, F0);                              \
        float xa1 = fmaf(g[G][3][i], C_SCALE, F0);                              \
        float xb1 = fmaf(g[G][2][i], C_SCALE, F1);                              \
        float xa2 = fmaf(g[G][5][i], C_SCALE, F1);                              \
        float xb2 = fmaf(g[G][4][i], C_SCALE, F2);                              \
        float xa3 = fmaf(g[G][7][i], C_SCALE, F2);                              \
        float xb3 = fmaf(g[G][6][i], C_SCALE, F3);                              \
        F0 = lae2(xa0, xb0);                                                    \
        F1 = lae2(xa1, xb1);                                                    \
        F2 = lae2(xa2, xb2);                                                    \
        F3 = lae2(xa3, xb3);                                                    \
    }                                                                           \
} while (0)

    // ---- staging (wave0): transpose via per-lane global source address ----
    // instr k, lane l: f = 16k + (l>>2), tsub = l&3; linear LDS dst = [f][t].
    const int tt = lane & 3;
    const float* gk0 = x + (size_t)b * NF + (lane >> 2);

    auto stage_half = [&](int ss) {   // stage superstep ss's 10 windows
        const int h = ss & 1;
        #pragma unroll
        for (int win = 0; win < WPS; ++win) {
            const int t = (ss * WPS + win) * 4 + tt;      // <= 3999 always
            const size_t toff = (size_t)t * (NB * NF);
            auto dst = (__attribute__((address_space(3))) char*)&xbuf[h][win][0];
            __builtin_amdgcn_global_load_lds(
                (const __attribute__((address_space(1))) void*)(gk0 + toff),
                (__attribute__((address_space(3))) void*)(dst), 4, 0, 0);
            __builtin_amdgcn_global_load_lds(
                (const __attribute__((address_space(1))) void*)(gk0 + 16 + toff),
                (__attribute__((address_space(3))) void*)(dst + 256), 4, 0, 0);
            if (lane < 32)
                __builtin_amdgcn_global_load_lds(
                    (const __attribute__((address_space(1))) void*)(gk0 + 32 + toff),
                    (__attribute__((address_space(3))) void*)(dst + 512), 4, 0, 0);
        }
    };

    // publish range: wave w's right boundary = wave w+1's ghost start.
    const int rb = OWN * (wv + 1) - GH;

#define PUB(FV, J, PAR) do {                                                    \
    unsigned o_ = (unsigned)(pb + (J) - rb);                                    \
    if (o_ < (unsigned)GH) exh[PAR][wv][o_] = (FV);                             \
} while (0)

    // Window body: prefetch window W+1, drain window W's 8 reads (in-order
    // LDS returns; counted wait), fence the scheduler, compute window W.
#define WINBODY(H, W) do {                                                      \
    GATHER(H, (W) + 1, ((W) + 1) & 1);                                          \
    asm volatile("s_waitcnt lgkmcnt(8)" ::: "memory");                          \
    __builtin_amdgcn_sched_barrier(0);                                          \
    COMPUTE((W) & 1);                                                           \
} while (0)

#define SUPER(H) do {                                                           \
    const int ss = s + (H);                                                     \
    if (wv == 0 && ss < NSS - 1) stage_half(ss + 1);  /* into half 1-H */       \
    GATHER(H, 0, 0);                                                            \
    WINBODY(H, 0); WINBODY(H, 1); WINBODY(H, 2); WINBODY(H, 3);                 \
    WINBODY(H, 4); WINBODY(H, 5); WINBODY(H, 6); WINBODY(H, 7);                 \
    WINBODY(H, 8);                                                              \
    asm volatile("s_waitcnt lgkmcnt(0)" ::: "memory"); /* window 9 landed */    \
    __builtin_amdgcn_sched_barrier(0);                                          \
    COMPUTE(1);                                        /* window 9 (9&1) */     \
    if (wv < 3) { PUB(F0, 0, H); PUB(F1, 1, H); PUB(F2, 2, H); PUB(F3, 3, H); } \
    asm volatile("s_waitcnt vmcnt(0)" ::: "memory");   /* landed long ago */    \
    asm volatile("s_waitcnt lgkmcnt(0)" ::: "memory"); /* PUB writes done */    \
    __builtin_amdgcn_sched_barrier(0);                                          \
    __builtin_amdgcn_s_barrier();                                               \
    asm volatile("" ::: "memory");                                              \
    if (wv >= 1 && lane < GH / 4) {                    /* refresh 40-pos ghost */\
        F0 = exh[H][wv - 1][4 * lane + 0];                                      \
        F1 = exh[H][wv - 1][4 * lane + 1];                                      \
        F2 = exh[H][wv - 1][4 * lane + 2];                                      \
        F3 = exh[H][wv - 1][4 * lane + 3];                                      \
    }                                                                           \
} while (0)

    // ---- prologue: superstep 0's half staged & landed ----
    if (wv == 0) {
        stage_half(0);
        asm volatile("s_waitcnt vmcnt(0)" ::: "memory");
    }
    asm volatile("s_waitcnt lgkmcnt(0)" ::: "memory");
    __builtin_amdgcn_sched_barrier(0);
    __builtin_amdgcn_s_barrier();
    asm volatile("" ::: "memory");

    for (int s = 0; s < NSS; s += 2) {
        SUPER(0);
        SUPER(1);
    }

#undef SUPER
#undef WINBODY
#undef PUB
#undef COMPUTE
#undef GATHER
#undef DSR

    // ---- output: own range [125*wv, 125*wv+125) tiles 0..499 exactly ----
    const int pf = seqlens[b] - 1;
    const int lo = OWN * wv;
    if (pf >= lo && pf < lo + OWN) {
        if      (pf == pb + 0) out[b] = F0 * OUT_SCALE;
        else if (pf == pb + 1) out[b] = F1 * OUT_SCALE;
        else if (pf == pb + 2) out[b] = F2 * OUT_SCALE;
        else if (pf == pb + 3) out[b] = F3 * OUT_SCALE;
    }
}

extern "C" void kernel_launch(void* const* d_in, const int* in_sizes, int n_in,
                              void* d_out, int out_size, void* d_ws, size_t ws_size,
                              hipStream_t stream) {
    const float* x        = (const float*)d_in[0];
    const int*   move_idx = (const int*)d_in[1];
    const int*   stay_idx = (const int*)d_in[2];
    const int*   seqlens  = (const int*)d_in[3];
    float*       out      = (float*)d_out;

    flipflop_fwd<<<dim3(NB), dim3(256), 0, stream>>>(x, move_idx, stay_idx, seqlens, out);
}

// Round 12
// 523.909 us; speedup vs baseline: 1.0077x; 1.0077x over previous
//
#include <hip/hip_runtime.h>

// FlipFlopLoss forward DP, round 9 = R8 superstep structure + the missing
// lgkmcnt discipline for inline-asm ds_read (R8's NaN root cause).
//
// new[p] = logaddexp(prev[p-1] + x[move_idx[p-1]], prev[p] + x[stay_idx[p]])
//
// 1 block/batch, 4 waves x 4 positions/lane. Wave w covers 256 positions from
// startw = 125w-40 (wave0: 0), owns [125w, 125w+125). Ghost depth 40 => ONE
// barrier per 40 steps (superstep = 10 windows x 4 steps). Wave w publishes
// exact positions [125(w+1)-40, 125(w+1)) pre-barrier; wave w+1 lanes 0..9
// refresh their ghost post-barrier.
// x staged into 2 half-buffers of 10 windows (f32x4 time-minor, transposed
// for free by global_load_lds per-lane source addressing). Wave0 issues next
// superstep's 30 loads at superstep TOP; vmcnt(0) at the boundary is free.
//
// R9 fix: the compiler inserts NO waitcnt for asm-volatile ds_read outputs.
// Every GATHER prefetch is now followed by s_waitcnt lgkmcnt(8) (drains the
// PREVIOUS window's 8 reads; LDS returns in-order) + sched_barrier(0) so
// hipcc can't hoist the dependent VALU above the wait (guide rule #18).
// Last window: lgkmcnt(0) before COMPUTE. R6/R7 were only correct because
// their per-window lgkmcnt(0)+barrier sat between GATHER and use.

typedef float f32x4 __attribute__((ext_vector_type(4)));

constexpr int NT   = 4000;
constexpr int NB   = 128;
constexpr int NF   = 40;
constexpr int NPOS = 500;
constexpr int WPS  = 10;            // windows per superstep
constexpr int NSS  = NT / (WPS*4);  // 100 supersteps
constexpr int OWN  = 125;
constexpr int GH   = 40;
constexpr float C_SCALE   = 1.4426950408889634f;           // SHARP * log2(e)
constexpr float OUT_SCALE = -0.6931471805599453f / 4000.f; // -ln2 / (SHARP*NT)
constexpr float NEGF = -1e30f;

__device__ __forceinline__ float dpp_shr1(float v) {
    // lane i gets lane i-1's v; lane 0 keeps old = NEGF (bound_ctrl=0).
    int r = __builtin_amdgcn_update_dpp(
        __float_as_int(NEGF), __float_as_int(v),
        0x138 /*wave_shr:1*/, 0xF, 0xF, false);
    return __int_as_float(r);
}

__device__ __forceinline__ float lae2(float A, float B) {
    float mx = fmaxf(A, B);
    float d  = A - B;
    return mx + __log2f(1.0f + exp2f(-fabsf(d)));   // neg/abs fold into v_exp
}

__global__ void __launch_bounds__(256, 1) flipflop_fwd(
    const float* __restrict__ x,         // [NT, NB, NF]
    const int*   __restrict__ move_idx,  // [NB, NPOS-1]
    const int*   __restrict__ stay_idx,  // [NB, NPOS]
    const int*   __restrict__ seqlens,   // [NB]
    float*       __restrict__ out)       // [NB]
{
    const int b    = blockIdx.x;
    const int tid  = threadIdx.x;
    const int lane = tid & 63;
    const int wv   = tid >> 6;

    __shared__ f32x4 xbuf[2][WPS][NF];  // [half][win][f] -> 4 t-values; 12.8KB
    __shared__ float exh[2][3][GH];     // [superstep parity][boundary][40]

    // ---- position mapping ----
    const int startw = (wv == 0) ? 0 : (OWN * wv - GH);
    const int pb = startw + 4 * lane;   // this lane's first position

    // per-position gather indices (positions > 499 clamped; values unused)
    const int q0 = pb + 0 > 499 ? 499 : pb + 0;
    const int q1 = pb + 1 > 499 ? 499 : pb + 1;
    const int q2 = pb + 2 > 499 ? 499 : pb + 2;
    const int q3 = pb + 3 > 499 ? 499 : pb + 3;
    const int s0 = stay_idx[b * NPOS + q0];
    const int s1 = stay_idx[b * NPOS + q1];
    const int s2 = stay_idx[b * NPOS + q2];
    const int s3 = stay_idx[b * NPOS + q3];
    const int m0 = move_idx[b * (NPOS - 1) + (q0 >= 1 ? q0 - 1 : 0)];
    const int m1 = move_idx[b * (NPOS - 1) + (q1 >= 1 ? q1 - 1 : 0)];
    const int m2 = move_idx[b * (NPOS - 1) + (q2 >= 1 ? q2 - 1 : 0)];
    const int m3 = move_idx[b * (NPOS - 1) + (q3 >= 1 ? q3 - 1 : 0)];

    float F0 = (pb == 0) ? 0.0f : NEGF;
    float F1 = NEGF, F2 = NEGF, F3 = NEGF;

    // ---- LDS gather addresses: buf base + idx*16; (half,win) via offset: ----
    unsigned base_u = (unsigned)(unsigned long long)
        (__attribute__((address_space(3))) char*)&xbuf[0][0][0];
    const unsigned aS0 = base_u + (unsigned)s0 * 16u;
    const unsigned aM0 = base_u + (unsigned)m0 * 16u;
    const unsigned aS1 = base_u + (unsigned)s1 * 16u;
    const unsigned aM1 = base_u + (unsigned)m1 * 16u;
    const unsigned aS2 = base_u + (unsigned)s2 * 16u;
    const unsigned aM2 = base_u + (unsigned)m2 * 16u;
    const unsigned aS3 = base_u + (unsigned)s3 * 16u;
    const unsigned aM3 = base_u + (unsigned)m3 * 16u;

    f32x4 g[2][8];   // [win parity][s0,m0,s1,m1,s2,m2,s3,m3]; static idx only

#define DSR(DST, ADDR, OFS)                                                     \
    asm volatile("ds_read_b128 %0, %1 offset:%c2"                               \
                 : "=v"(DST) : "v"(ADDR), "i"(OFS))

#define GATHER(H, WIN, G) do {                                                  \
    DSR(g[G][0], aS0, ((H) * WPS + (WIN)) * 640);                               \
    DSR(g[G][1], aM0, ((H) * WPS + (WIN)) * 640);                               \
    DSR(g[G][2], aS1, ((H) * WPS + (WIN)) * 640);                               \
    DSR(g[G][3], aM1, ((H) * WPS + (WIN)) * 640);                               \
    DSR(g[G][4], aS2, ((H) * WPS + (WIN)) * 640);                               \
    DSR(g[G][5], aM2, ((H) * WPS + (WIN)) * 640);                               \
    DSR(g[G][6], aS3, ((H) * WPS + (WIN)) * 640);                               \
    DSR(g[G][7], aM3, ((H) * WPS + (WIN)) * 640);                               \
} while (0)

#define COMPUTE(G) do {                                                         \
    _Pragma("unroll")                                                           \
    for (int i = 0; i < 4; ++i) {                                               \
        float nb = dpp_shr1(F3);                                                \
        float xa0 = fmaf(g[G][1][i], C_SCALE, nb);                              \
        float xb0 = fmaf(g[G][0][i], C_SCALE, F0);                              \
        float xa1 = fmaf(g[G][3][i], C_SCALE, F0);                              \
        float xb1 = fmaf(g[G][2][i], C_SCALE, F1);                              \
        float xa2 = fmaf(g[G][5][i], C_SCALE, F1);                              \
        float xb2 = fmaf(g[G][4][i], C_SCALE, F2);                              \
        float xa3 = fmaf(g[G][7][i], C_SCALE, F2);                              \
        float xb3 = fmaf(g[G][6][i], C_SCALE, F3);                              \
        F0 = lae2(xa0, xb0);                                                    \
        F1 = lae2(xa1, xb1);                                                    \
        F2 = lae2(xa2, xb2);                                                    \
        F3 = lae2(xa3, xb3);                                                    \
    }                                                                           \
} while (0)

    // ---- staging (wave0): transpose via per-lane global source address ----
    // instr k, lane l: f = 16k + (l>>2), tsub = l&3; linear LDS dst = [f][t].
    const int tt = lane & 3;
    const float* gk0 = x + (size_t)b * NF + (lane >> 2);

    auto stage_half = [&](int ss) {   // stage superstep ss's 10 windows
        const int h = ss & 1;
        #pragma unroll
        for (int win = 0; win < WPS; ++win) {
            const int t = (ss * WPS + win) * 4 + tt;      // <= 3999 always
            const size_t toff = (size_t)t * (NB * NF);
            auto dst = (__attribute__((address_space(3))) char*)&xbuf[h][win][0];
            __builtin_amdgcn_global_load_lds(
                (const __attribute__((address_space(1))) void*)(gk0 + toff),
                (__attribute__((address_space(3))) void*)(dst), 4, 0, 0);
            __builtin_amdgcn_global_load_lds(
                (const __attribute__((address_space(1))) void*)(gk0 + 16 + toff),
                (__attribute__((address_space(3))) void*)(dst + 256), 4, 0, 0);
            if (lane < 32)
                __builtin_amdgcn_global_load_lds(
                    (const __attribute__((address_space(1))) void*)(gk0 + 32 + toff),
                    (__attribute__((address_space(3))) void*)(dst + 512), 4, 0, 0);
        }
    };

    // publish range: wave w's right boundary = wave w+1's ghost start.
    const int rb = OWN * (wv + 1) - GH;

#define PUB(FV, J, PAR) do {                                                    \
    unsigned o_ = (unsigned)(pb + (J) - rb);                                    \
    if (o_ < (unsigned)GH) exh[PAR][wv][o_] = (FV);                             \
} while (0)

    // Window body: prefetch window W+1, drain window W's 8 reads (in-order
    // LDS returns; counted wait), fence the scheduler, compute window W.
#define WINBODY(H, W) do {                                                      \
    GATHER(H, (W) + 1, ((W) + 1) & 1);                                          \
    asm volatile("s_waitcnt lgkmcnt(8)" ::: "memory");                          \
    __builtin_amdgcn_sched_barrier(0);                                          \
    COMPUTE((W) & 1);                                                           \
} while (0)

#define SUPER(H) do {                                                           \
    const int ss = s + (H);                                                     \
    if (wv == 0 && ss < NSS - 1) stage_half(ss + 1);  /* into half 1-H */       \
    GATHER(H, 0, 0);                                                            \
    WINBODY(H, 0); WINBODY(H, 1); WINBODY(H, 2); WINBODY(H, 3);                 \
    WINBODY(H, 4); WINBODY(H, 5); WINBODY(H, 6); WINBODY(H, 7);                 \
    WINBODY(H, 8);                                                              \
    asm volatile("s_waitcnt lgkmcnt(0)" ::: "memory"); /* window 9 landed */    \
    __builtin_amdgcn_sched_barrier(0);                                          \
    COMPUTE(1);                                        /* window 9 (9&1) */     \
    if (wv < 3) { PUB(F0, 0, H); PUB(F1, 1, H); PUB(F2, 2, H); PUB(F3, 3, H); } \
    asm volatile("s_waitcnt vmcnt(0)" ::: "memory");   /* landed long ago */    \
    asm volatile("s_waitcnt lgkmcnt(0)" ::: "memory"); /* PUB writes done */    \
    __builtin_amdgcn_sched_barrier(0);                                          \
    __builtin_amdgcn_s_barrier();                                               \
    asm volatile("" ::: "memory");                                              \
    if (wv >= 1 && lane < GH / 4) {                    /* refresh 40-pos ghost */\
        F0 = exh[H][wv - 1][4 * lane + 0];                                      \
        F1 = exh[H][wv - 1][4 * lane + 1];                                      \
        F2 = exh[H][wv - 1][4 * lane + 2];                                      \
        F3 = exh[H][wv - 1][4 * lane + 3];                                      \
    }                                                                           \
} while (0)

    // ---- prologue: superstep 0's half staged & landed ----
    if (wv == 0) {
        stage_half(0);
        asm volatile("s_waitcnt vmcnt(0)" ::: "memory");
    }
    asm volatile("s_waitcnt lgkmcnt(0)" ::: "memory");
    __builtin_amdgcn_sched_barrier(0);
    __builtin_amdgcn_s_barrier();
    asm volatile("" ::: "memory");

    for (int s = 0; s < NSS; s += 2) {
        SUPER(0);
        SUPER(1);
    }

#undef SUPER
#undef WINBODY
#undef PUB
#undef COMPUTE
#undef GATHER
#undef DSR

    // ---- output: own range [125*wv, 125*wv+125) tiles 0..499 exactly ----
    const int pf = seqlens[b] - 1;
    const int lo = OWN * wv;
    if (pf >= lo && pf < lo + OWN) {
        if      (pf == pb + 0) out[b] = F0 * OUT_SCALE;
        else if (pf == pb + 1) out[b] = F1 * OUT_SCALE;
        else if (pf == pb + 2) out[b] = F2 * OUT_SCALE;
        else if (pf == pb + 3) out[b] = F3 * OUT_SCALE;
    }
}

extern "C" void kernel_launch(void* const* d_in, const int* in_sizes, int n_in,
                              void* d_out, int out_size, void* d_ws, size_t ws_size,
                              hipStream_t stream) {
    const float* x        = (const float*)d_in[0];
    const int*   move_idx = (const int*)d_in[1];
    const int*   stay_idx = (const int*)d_in[2];
    const int*   seqlens  = (const int*)d_in[3];
    float*       out      = (float*)d_out;

    flipflop_fwd<<<dim3(NB), dim3(256), 0, stream>>>(x, move_idx, stay_idx, seqlens, out);
}